// Round 5
// baseline (474.412 us; speedup 1.0000x reference)
//
#include <hip/hip_runtime.h>

using u16 = unsigned short;
using u32 = unsigned int;

typedef __attribute__((ext_vector_type(4))) _Float16 f16x4;
typedef __attribute__((ext_vector_type(4))) float f32x4;
typedef __attribute__((ext_vector_type(2))) float f32x2;
typedef __attribute__((ext_vector_type(4))) u32 u32x4;
typedef __attribute__((ext_vector_type(2))) u32 u32x2;

// K=16 f16 MFMA: A[m=lane&15][k=4q+j] (2 VGPRs), B[k=4q+j][n=lane&15] (2 VGPRs),
// C/D col=lane&15, row=4q+r. Identity (HW-verified R4): packed C/D tile == next
// layer's B-frag. NO unions anywhere — they defeated SROA in R4 and pushed
// every fragment through scratch (1.07 GB HBM traffic). bit_cast only.
#define MFMA(a, b, c) __builtin_amdgcn_mfma_f32_16x16x16f16((a), (b), (c), 0, 0, 0)

__device__ __forceinline__ u16 f2h(float x) {
  _Float16 h = (_Float16)x; u16 r; __builtin_memcpy(&r, &h, 2); return r;
}

__device__ __forceinline__ float fast_tanh(float x) {
  // tanh(x) = 1 - 2/(1 + exp2(x * 2*log2(e)))
  float t = __builtin_amdgcn_exp2f(x * 2.885390081777927f);
  return __builtin_fmaf(-2.0f, __builtin_amdgcn_rcpf(1.0f + t), 1.0f);
}

__device__ __forceinline__ u32 pkrtz(float a, float b) {
  return __builtin_bit_cast(u32, __builtin_amdgcn_cvt_pkrtz(a, b));
}

__device__ __forceinline__ f16x4 tanh4pk(f32x4 z) {
  u32x2 p;
  p.x = pkrtz(fast_tanh(z[0]), fast_tanh(z[1]));
  p.y = pkrtz(fast_tanh(z[2]), fast_tanh(z[3]));
  return __builtin_bit_cast(f16x4, p);
}

__device__ __forceinline__ f16x4 frag_lo(u32x4 w) {
  u32x2 t; t.x = w.x; t.y = w.y; return __builtin_bit_cast(f16x4, t);
}
__device__ __forceinline__ f16x4 frag_hi(u32x4 w) {
  u32x2 t; t.x = w.z; t.y = w.w; return __builtin_bit_cast(f16x4, t);
}

// Weight LDS layout, per output-row n (256 B): 16B chunk CH = (4e+q)^(n&15)
// holds A-frag halves for ks'=2e (k=32e+4q..+3) and ks'=2e+1 (k=32e+16+4q..+3).
__device__ __forceinline__ int woff(int k, int n) {
  int e = k >> 5, q = (k >> 2) & 3, h = (k >> 4) & 1, j = k & 3;
  return n * 256 + ((((e << 2) + q) ^ (n & 15)) << 4) + (h << 3) + (j << 1);
}

#define LDS_W2   0
#define LDS_W3   32768
#define LDS_W4   65536      // 16 rows x 256B, rows >=2 zeroed
#define LDS_BIAS 69632      // [3][128] f32
#define LDS_TOTAL 71168

__global__ void __launch_bounds__(512, 4) mlp_fused(
    const float* __restrict__ Xg, const float* __restrict__ Yg,
    const float* __restrict__ C1g, const float* __restrict__ C2g,
    const float* __restrict__ W1g, const float* __restrict__ B1g,
    const float* __restrict__ W2g, const float* __restrict__ B2g,
    const float* __restrict__ W3g, const float* __restrict__ B3g,
    const float* __restrict__ W4g, const float* __restrict__ B4g,
    float* __restrict__ Og, int npts, int nwaves_total)
{
  extern __shared__ char lds[];
  const int tid = threadIdx.x;

  // ---- stage W2^T/W3^T frags, zero-padded W4^T, biases (f32) ----
  for (int i = tid; i < 16384; i += 512) {
    int k = i >> 7, n = i & 127;
    int off = woff(k, n);
    *(u16*)(lds + LDS_W2 + off) = f2h(W2g[i]);
    *(u16*)(lds + LDS_W3 + off) = f2h(W3g[i]);
  }
  for (int i = tid; i < 2048; i += 512) {
    int n = i >> 7, k = i & 127;                 // row n = output col of W4
    float v = (n < 2) ? W4g[k * 2 + n] : 0.f;
    *(u16*)(lds + LDS_W4 + woff(k, n)) = f2h(v);
  }
  if (tid < 384) {
    int L = tid >> 7, n = tid & 127;
    float v = (L == 0) ? B1g[n] : ((L == 1) ? B2g[n] : B3g[n]);
    *(float*)(lds + LDS_BIAS + tid * 4) = v;
  }
  __syncthreads();

  const int wave = tid >> 6;
  const int lane = tid & 63;
  const int q = lane >> 4;
  const int c = lane & 15;
  const int wgid = blockIdx.x * 8 + wave;

  // ---- W1^T A-frags in registers: lane(q=0,c): k=0..3 of column n=16nt+c ----
  f16x4 w1f[8];
#pragma unroll
  for (int nt = 0; nt < 8; nt++) {
    int n = nt * 16 + c;
    f16x4 w;
    w[0] = (_Float16)W1g[n];       w[1] = (_Float16)W1g[128 + n];
    w[2] = (_Float16)W1g[256 + n]; w[3] = (_Float16)W1g[384 + n];
    f16x4 z = {(_Float16)0.f, (_Float16)0.f, (_Float16)0.f, (_Float16)0.f};
    w1f[nt] = (q == 0) ? w : z;
  }
  const float b40 = B4g[0], b41 = B4g[1];

  const int nbatch = npts >> 5;   // 32 points (2 column-tiles of 16) per iter
  for (int b = wgid; b < nbatch; b += nwaves_total) {
    const int pbase = b << 5;

    // ---- layer 1: Z1^T = W1^T * X^T (+b1 via C operand) ----
    f16x4 xb0, xb1;
    {
      f16x4 z = {(_Float16)0.f, (_Float16)0.f, (_Float16)0.f, (_Float16)0.f};
      xb0 = z; xb1 = z;
      if (q == 0) {
        int i0 = pbase + c, i1 = pbase + 16 + c;
        xb0[0] = (_Float16)Xg[i0];  xb0[1] = (_Float16)Yg[i0];
        xb0[2] = (_Float16)C1g[i0]; xb0[3] = (_Float16)C2g[i0];
        xb1[0] = (_Float16)Xg[i1];  xb1[1] = (_Float16)Yg[i1];
        xb1[2] = (_Float16)C1g[i1]; xb1[3] = (_Float16)C2g[i1];
      }
    }
    f16x4 H0[8], H1[8];
#pragma unroll
    for (int nt = 0; nt < 8; nt++) {
      f32x4 bb = *(const f32x4*)(lds + LDS_BIAS + nt * 64 + q * 16);
      f32x4 a0 = MFMA(w1f[nt], xb0, bb);
      f32x4 a1 = MFMA(w1f[nt], xb1, bb);
      H0[nt] = tanh4pk(a0);
      H1[nt] = tanh4pk(a1);
    }

    // ---- layers 2 and 3: Z^T = W^T * H^T, H-frags stay in registers ----
#pragma unroll
    for (int L = 0; L < 2; L++) {
      const char* wl = lds + (L ? LDS_W3 : LDS_W2);
      const char* bl = lds + LDS_BIAS + (L + 1) * 512;
      f16x4 N0[8], N1[8];
#pragma unroll
      for (int nt = 0; nt < 8; nt++) {
        f32x4 bb = *(const f32x4*)(bl + nt * 64 + q * 16);
        f32x4 a0 = bb, a1 = bb;
        const char* wrow = wl + (nt * 16 + c) * 256;
#pragma unroll
        for (int e = 0; e < 4; e++) {
          u32x4 w = *(const u32x4*)(wrow + ((((e << 2) + q) ^ c) << 4));
          f16x4 wa = frag_lo(w), wb = frag_hi(w);
          a0 = MFMA(wa, H0[2 * e], a0);
          a0 = MFMA(wb, H0[2 * e + 1], a0);
          a1 = MFMA(wa, H1[2 * e], a1);
          a1 = MFMA(wb, H1[2 * e + 1], a1);
        }
        N0[nt] = tanh4pk(a0);
        N1[nt] = tanh4pk(a1);
      }
#pragma unroll
      for (int nt = 0; nt < 8; nt++) { H0[nt] = N0[nt]; H1[nt] = N1[nt]; }
    }

    // ---- layer 4: Z4^T = W4^T * H3^T (rows 0,1 valid) + store f32 ----
    {
      f32x4 a0 = {b40, b41, 0.f, 0.f};
      f32x4 a1 = a0;
      const char* wrow = lds + LDS_W4 + c * 256;
#pragma unroll
      for (int e = 0; e < 4; e++) {
        u32x4 w = *(const u32x4*)(wrow + ((((e << 2) + q) ^ c) << 4));
        f16x4 wa = frag_lo(w), wb = frag_hi(w);
        a0 = MFMA(wa, H0[2 * e], a0);
        a0 = MFMA(wb, H0[2 * e + 1], a0);
        a1 = MFMA(wa, H1[2 * e], a1);
        a1 = MFMA(wb, H1[2 * e + 1], a1);
      }
      if (q == 0) {   // lane c holds logits of its point in acc[0], acc[1]
        f32x2 s0 = {a0[0], a0[1]};
        f32x2 s1 = {a1[0], a1[1]};
        *(f32x2*)(Og + (size_t)(pbase + c) * 2) = s0;
        *(f32x2*)(Og + (size_t)(pbase + 16 + c) * 2) = s1;
      }
    }
  }
}

extern "C" void kernel_launch(void* const* d_in, const int* in_sizes, int n_in,
                              void* d_out, int out_size, void* d_ws, size_t ws_size,
                              hipStream_t stream)
{
  (void)n_in; (void)out_size; (void)d_ws; (void)ws_size;
  const float* X  = (const float*)d_in[0];
  const float* Y  = (const float*)d_in[1];
  const float* C1 = (const float*)d_in[2];
  const float* C2 = (const float*)d_in[3];
  const float* W1 = (const float*)d_in[4];
  const float* B1 = (const float*)d_in[5];
  const float* W2 = (const float*)d_in[6];
  const float* B2 = (const float*)d_in[7];
  const float* W3 = (const float*)d_in[8];
  const float* B3 = (const float*)d_in[9];
  const float* W4 = (const float*)d_in[10];
  const float* B4 = (const float*)d_in[11];
  int npts = in_sizes[0];
  const int nblk = 512;               // 69.5KB LDS -> 2 blocks/CU -> 16 waves/CU
  const int nwaves = nblk * 8;
  hipLaunchKernelGGL(mlp_fused, dim3(nblk), dim3(512), LDS_TOTAL, stream,
                     X, Y, C1, C2, W1, B1, W2, B2, W3, B3, W4, B4,
                     (float*)d_out, npts, nwaves);
}

// Round 6
// 265.534 us; speedup vs baseline: 1.7866x; 1.7866x over previous
//
#include <hip/hip_runtime.h>

using u16 = unsigned short;
using u32 = unsigned int;

typedef __attribute__((ext_vector_type(4))) _Float16 f16x4;
typedef __attribute__((ext_vector_type(4))) float f32x4;
typedef __attribute__((ext_vector_type(2))) float f32x2;
typedef __attribute__((ext_vector_type(4))) u32 u32x4;
typedef __attribute__((ext_vector_type(2))) u32 u32x2;

// K=16 f16 MFMA: A[m=lane&15][k=4q+j] (2 VGPRs), B[k=4q+j][n=lane&15] (2 VGPRs),
// C/D col=lane&15, row=4q+r. Identity (HW-verified R4): packed C/D tile == next
// layer's B-frag.
// LESSON (R4/R5): __launch_bounds__(512, 4) capped the allocator at 64 VGPRs
// (backend treated arg as 4 blocks/CU -> 32 waves/CU -> 2048/32 = 64) and the
// ~120 live registers spilled to scratch: 1.07 GB HBM traffic, 4x regression.
// Plain __launch_bounds__(512) lets the allocator take what it needs (R2: 80).
#define MFMA(a, b, c) __builtin_amdgcn_mfma_f32_16x16x16f16((a), (b), (c), 0, 0, 0)

__device__ __forceinline__ u16 f2h(float x) {
  _Float16 h = (_Float16)x; u16 r; __builtin_memcpy(&r, &h, 2); return r;
}

__device__ __forceinline__ float fast_tanh(float x) {
  // tanh(x) = 1 - 2/(1 + exp2(x * 2*log2(e)))
  float t = __builtin_amdgcn_exp2f(x * 2.885390081777927f);
  return __builtin_fmaf(-2.0f, __builtin_amdgcn_rcpf(1.0f + t), 1.0f);
}

__device__ __forceinline__ u32 pkrtz(float a, float b) {
  return __builtin_bit_cast(u32, __builtin_amdgcn_cvt_pkrtz(a, b));
}

__device__ __forceinline__ f16x4 tanh4pk(f32x4 z) {
  u32x2 p;
  p.x = pkrtz(fast_tanh(z[0]), fast_tanh(z[1]));
  p.y = pkrtz(fast_tanh(z[2]), fast_tanh(z[3]));
  return __builtin_bit_cast(f16x4, p);
}

__device__ __forceinline__ f16x4 frag_lo(u32x4 w) {
  u32x2 t; t.x = w.x; t.y = w.y; return __builtin_bit_cast(f16x4, t);
}
__device__ __forceinline__ f16x4 frag_hi(u32x4 w) {
  u32x2 t; t.x = w.z; t.y = w.w; return __builtin_bit_cast(f16x4, t);
}

// Weight LDS layout, per output-row n (256 B): 16B chunk CH = (4e+q)^(n&15)
// holds A-frag halves for ks'=2e (k=32e+4q..+3) and ks'=2e+1 (k=32e+16+4q..+3).
__device__ __forceinline__ int woff(int k, int n) {
  int e = k >> 5, q = (k >> 2) & 3, h = (k >> 4) & 1, j = k & 3;
  return n * 256 + ((((e << 2) + q) ^ (n & 15)) << 4) + (h << 3) + (j << 1);
}

#define LDS_W2   0
#define LDS_W3   32768
#define LDS_W4   65536      // 16 rows x 256B, rows >=2 zeroed
#define LDS_BIAS 69632      // [3][128] f32
#define LDS_TOTAL 71168

__global__ void __launch_bounds__(512) mlp_fused(
    const float* __restrict__ Xg, const float* __restrict__ Yg,
    const float* __restrict__ C1g, const float* __restrict__ C2g,
    const float* __restrict__ W1g, const float* __restrict__ B1g,
    const float* __restrict__ W2g, const float* __restrict__ B2g,
    const float* __restrict__ W3g, const float* __restrict__ B3g,
    const float* __restrict__ W4g, const float* __restrict__ B4g,
    float* __restrict__ Og, int npts, int nwaves_total)
{
  extern __shared__ char lds[];
  const int tid = threadIdx.x;

  // ---- stage W2^T/W3^T frags, zero-padded W4^T, biases (f32) ----
  for (int i = tid; i < 16384; i += 512) {
    int k = i >> 7, n = i & 127;
    int off = woff(k, n);
    *(u16*)(lds + LDS_W2 + off) = f2h(W2g[i]);
    *(u16*)(lds + LDS_W3 + off) = f2h(W3g[i]);
  }
  for (int i = tid; i < 2048; i += 512) {
    int n = i >> 7, k = i & 127;                 // row n = output col of W4
    float v = (n < 2) ? W4g[k * 2 + n] : 0.f;
    *(u16*)(lds + LDS_W4 + woff(k, n)) = f2h(v);
  }
  if (tid < 384) {
    int L = tid >> 7, n = tid & 127;
    float v = (L == 0) ? B1g[n] : ((L == 1) ? B2g[n] : B3g[n]);
    *(float*)(lds + LDS_BIAS + tid * 4) = v;
  }
  __syncthreads();

  const int wave = tid >> 6;
  const int lane = tid & 63;
  const int q = lane >> 4;
  const int c = lane & 15;
  const int wgid = blockIdx.x * 8 + wave;

  // ---- W1^T A-frags in registers: lane(q=0,c): k=0..3 of column n=16nt+c ----
  f16x4 w1f[8];
#pragma unroll
  for (int nt = 0; nt < 8; nt++) {
    int n = nt * 16 + c;
    f16x4 w;
    w[0] = (_Float16)W1g[n];       w[1] = (_Float16)W1g[128 + n];
    w[2] = (_Float16)W1g[256 + n]; w[3] = (_Float16)W1g[384 + n];
    f16x4 z = {(_Float16)0.f, (_Float16)0.f, (_Float16)0.f, (_Float16)0.f};
    w1f[nt] = (q == 0) ? w : z;
  }
  const float b40 = B4g[0], b41 = B4g[1];

  const int nbatch = npts >> 5;   // 32 points (2 column-tiles of 16) per iter
  for (int b = wgid; b < nbatch; b += nwaves_total) {
    const int pbase = b << 5;

    // ---- layer 1: Z1^T = W1^T * X^T (+b1 via C operand) ----
    f16x4 xb0, xb1;
    {
      f16x4 z = {(_Float16)0.f, (_Float16)0.f, (_Float16)0.f, (_Float16)0.f};
      xb0 = z; xb1 = z;
      if (q == 0) {
        int i0 = pbase + c, i1 = pbase + 16 + c;
        xb0[0] = (_Float16)Xg[i0];  xb0[1] = (_Float16)Yg[i0];
        xb0[2] = (_Float16)C1g[i0]; xb0[3] = (_Float16)C2g[i0];
        xb1[0] = (_Float16)Xg[i1];  xb1[1] = (_Float16)Yg[i1];
        xb1[2] = (_Float16)C1g[i1]; xb1[3] = (_Float16)C2g[i1];
      }
    }
    f16x4 H0[8], H1[8];
#pragma unroll
    for (int nt = 0; nt < 8; nt++) {
      f32x4 bb = *(const f32x4*)(lds + LDS_BIAS + nt * 64 + q * 16);
      f32x4 a0 = MFMA(w1f[nt], xb0, bb);
      f32x4 a1 = MFMA(w1f[nt], xb1, bb);
      H0[nt] = tanh4pk(a0);
      H1[nt] = tanh4pk(a1);
    }

    // ---- layers 2 and 3: Z^T = W^T * H^T, H-frags stay in registers ----
#pragma unroll
    for (int L = 0; L < 2; L++) {
      const char* wl = lds + (L ? LDS_W3 : LDS_W2);
      const char* bl = lds + LDS_BIAS + (L + 1) * 512;
      f16x4 N0[8], N1[8];
#pragma unroll
      for (int nt = 0; nt < 8; nt++) {
        f32x4 bb = *(const f32x4*)(bl + nt * 64 + q * 16);
        f32x4 a0 = bb, a1 = bb;
        const char* wrow = wl + (nt * 16 + c) * 256;
#pragma unroll
        for (int e = 0; e < 4; e++) {
          u32x4 w = *(const u32x4*)(wrow + ((((e << 2) + q) ^ c) << 4));
          f16x4 wa = frag_lo(w), wb = frag_hi(w);
          a0 = MFMA(wa, H0[2 * e], a0);
          a0 = MFMA(wb, H0[2 * e + 1], a0);
          a1 = MFMA(wa, H1[2 * e], a1);
          a1 = MFMA(wb, H1[2 * e + 1], a1);
        }
        N0[nt] = tanh4pk(a0);
        N1[nt] = tanh4pk(a1);
      }
#pragma unroll
      for (int nt = 0; nt < 8; nt++) { H0[nt] = N0[nt]; H1[nt] = N1[nt]; }
    }

    // ---- layer 4: Z4^T = W4^T * H3^T (rows 0,1 valid) + store f32 ----
    {
      f32x4 a0 = {b40, b41, 0.f, 0.f};
      f32x4 a1 = a0;
      const char* wrow = lds + LDS_W4 + c * 256;
#pragma unroll
      for (int e = 0; e < 4; e++) {
        u32x4 w = *(const u32x4*)(wrow + ((((e << 2) + q) ^ c) << 4));
        f16x4 wa = frag_lo(w), wb = frag_hi(w);
        a0 = MFMA(wa, H0[2 * e], a0);
        a0 = MFMA(wb, H0[2 * e + 1], a0);
        a1 = MFMA(wa, H1[2 * e], a1);
        a1 = MFMA(wb, H1[2 * e + 1], a1);
      }
      if (q == 0) {   // lane c holds logits of its point in acc[0], acc[1]
        f32x2 s0 = {a0[0], a0[1]};
        f32x2 s1 = {a1[0], a1[1]};
        *(f32x2*)(Og + (size_t)(pbase + c) * 2) = s0;
        *(f32x2*)(Og + (size_t)(pbase + 16 + c) * 2) = s1;
      }
    }
  }
}

extern "C" void kernel_launch(void* const* d_in, const int* in_sizes, int n_in,
                              void* d_out, int out_size, void* d_ws, size_t ws_size,
                              hipStream_t stream)
{
  (void)n_in; (void)out_size; (void)d_ws; (void)ws_size;
  const float* X  = (const float*)d_in[0];
  const float* Y  = (const float*)d_in[1];
  const float* C1 = (const float*)d_in[2];
  const float* C2 = (const float*)d_in[3];
  const float* W1 = (const float*)d_in[4];
  const float* B1 = (const float*)d_in[5];
  const float* W2 = (const float*)d_in[6];
  const float* B2 = (const float*)d_in[7];
  const float* W3 = (const float*)d_in[8];
  const float* B3 = (const float*)d_in[9];
  const float* W4 = (const float*)d_in[10];
  const float* B4 = (const float*)d_in[11];
  int npts = in_sizes[0];
  const int nblk = 512;               // 69.5KB LDS -> 2 blocks/CU -> 16 waves/CU
  const int nwaves = nblk * 8;
  hipLaunchKernelGGL(mlp_fused, dim3(nblk), dim3(512), LDS_TOTAL, stream,
                     X, Y, C1, C2, W1, B1, W2, B2, W3, B3, W4, B4,
                     (float*)d_out, npts, nwaves);
}